// Round 4
// baseline (1681.097 us; speedup 1.0000x reference)
//
#include <hip/hip_runtime.h>
#include <math.h>

// Problem dims
#define TT 100
#define BB 64
#define II 256
#define HH 512
#define G4H 2048   // 4H
#define G3H 1536   // 3H
#define NBLK 256   // persistent recurrence blocks (= HH/2)

// ---- workspace layout (float offsets) ----
// G_T   [T][4H][B]   gates from x@Wih^T + biases, layout [t][j][b]
// DbufT [B][T][3H]   (aliases G_T region after step loop — G_T dead by then)
// Hbuf  [T+1][H][B]  h history transposed; slot 0 = initial_h^T
// Fbuf  [T][H][B]    f gates
// Dbuf  [T][3H][B]   d values (scaled in-place to \tilde{d})
// cT    [H][B]
// xT    [T][I][B]    (WhhG aliases xT region after gx GEMM — xT dead by then)
// WihT  [I][4H]      (bar[] aliases WihT after gx GEMM — WihT dead by then)
// WhhT  [H][4H]
#define OFF_GT    0
#define OFF_HBUF  13107200
#define OFF_FBUF  16416768
#define OFF_DBUF  19693568
#define OFF_CT    29523968
#define OFF_XT    29556736
#define OFF_WIHT  31195136
#define OFF_WHHT  31719424

// ---- output layout (float offsets in d_out) ----
#define O_OUT   0          // outputs [T][B][H]
#define O_CX    3276800    // cx [B][H]
#define O_EVIH  3309568    // ev_ih [B][3H][I]
#define O_EVHH  28475392   // ev_hh [B][3H][H]
#define O_EVB   78807040   // ev_b  [B][3H]

// Generic 64x64 tiled transpose: dst[c][r] = src[r][c]. R,C multiples of 64.
__global__ __launch_bounds__(256) void tp64(const float* __restrict__ src,
                                            float* __restrict__ dst,
                                            int R, int C,
                                            long sstride, long dstride) {
  __shared__ float tile[64][65];
  src += (long)blockIdx.z * sstride;
  dst += (long)blockIdx.z * dstride;
  int r0 = blockIdx.y * 64, c0 = blockIdx.x * 64;
  int tx = threadIdx.x & 15, tq = threadIdx.x >> 4;
#pragma unroll
  for (int p = 0; p < 4; ++p) {
    int rl = p * 16 + tq;
    float4 v = *(const float4*)(src + (long)(r0 + rl) * C + c0 + tx * 4);
    tile[rl][tx * 4 + 0] = v.x; tile[rl][tx * 4 + 1] = v.y;
    tile[rl][tx * 4 + 2] = v.z; tile[rl][tx * 4 + 3] = v.w;
  }
  __syncthreads();
#pragma unroll
  for (int p = 0; p < 4; ++p) {
    int cl = p * 16 + tq;
    float4 v;
    v.x = tile[tx * 4 + 0][cl]; v.y = tile[tx * 4 + 1][cl];
    v.z = tile[tx * 4 + 2][cl]; v.w = tile[tx * 4 + 3][cl];
    *(float4*)(dst + (long)(c0 + cl) * R + r0 + tx * 4) = v;
  }
}

// WhhG[k][hh*4+g] = WhhT[k][g*512+hh]  (gate-interleaved for uniform dwordx4)
// Also zeroes the barrier slots (bar aliases dead WihT) for this replay.
__global__ __launch_bounds__(256) void make_whhg(const float* __restrict__ WhhT,
                                                 float* __restrict__ WhhG,
                                                 int* __restrict__ bar) {
  int gid = blockIdx.x * 256 + threadIdx.x;  // 512*2048 total
  if (gid < NBLK) bar[gid] = 0;
  int k = gid >> 11, j = gid & 2047;
  float v = WhhT[gid];
  WhhG[(long)k * G4H + ((j & 511) << 2) + (j >> 9)] = v;
}

// Tiled TN GEMM: C[m][n] = sum_k A[k][m] * Z[k][n]  (+ bias[m] if BIAS).
// Both operands stored K-major. 64x64 C-tile, 256 thr, 4x4 outputs/thread.
// ZSHIFT: Z row k maps to (k==0 ? Z0 : Z + (k-1)*ldz)  [for h_{t-1} history].
template <int BK, int KTILES, bool BIAS, bool ZSHIFT>
__global__ __launch_bounds__(256) void gemm_tn(
    const float* __restrict__ A, long batchA, int lda,
    const float* __restrict__ Z, long batchZ, int ldz,
    const float* __restrict__ Z0, long batchZ0,
    float* __restrict__ C, long batchC, int ldc,
    const float* __restrict__ bia, const float* __restrict__ bib) {
  __shared__ float As[BK][64];
  __shared__ float Zs[BK][64];
  int tid = threadIdx.x;
  int tn = tid & 15, tm = tid >> 4;
  int m0 = blockIdx.x * 64, n0 = blockIdx.y * 64;
  long bz = blockIdx.z;
  const float* Ab = A + bz * batchA + m0;
  const float* Zb = Z + bz * batchZ + n0;
  const float* Z0b = ZSHIFT ? (Z0 + bz * batchZ0 + n0) : nullptr;
  float acc[4][4] = {};
  for (int kt = 0; kt < KTILES; ++kt) {
    int k0 = kt * BK;
#pragma unroll
    for (int p = tid; p < BK * 64; p += 256) {
      int r = p >> 6, c = p & 63;
      int k = k0 + r;
      As[r][c] = Ab[(long)k * lda + c];
      const float* zr;
      if (ZSHIFT)
        zr = (k == 0) ? Z0b : (Zb + (long)(k - 1) * ldz);
      else
        zr = Zb + (long)k * ldz;
      Zs[r][c] = zr[c];
    }
    __syncthreads();
#pragma unroll 4
    for (int kk = 0; kk < BK; ++kk) {
      float4 a = *(const float4*)&As[kk][tm * 4];
      float4 z = *(const float4*)&Zs[kk][tn * 4];
      float av[4] = {a.x, a.y, a.z, a.w};
      float zv[4] = {z.x, z.y, z.z, z.w};
#pragma unroll
      for (int q = 0; q < 4; ++q)
#pragma unroll
        for (int r = 0; r < 4; ++r)
          acc[q][r] = fmaf(av[q], zv[r], acc[q][r]);
    }
    __syncthreads();
  }
  float* Cb = C + bz * batchC + n0 + tn * 4;
#pragma unroll
  for (int q = 0; q < 4; ++q) {
    int m = m0 + tm * 4 + q;
    float bv = BIAS ? (bia[m] + bib[m]) : 0.f;
    float4 v;
    v.x = acc[q][0] + bv; v.y = acc[q][1] + bv;
    v.z = acc[q][2] + bv; v.w = acc[q][3] + bv;
    *(float4*)(Cb + (long)m * ldc) = v;
  }
}

// ---- Persistent fused recurrence: all 100 steps in ONE kernel. ----
// Cooperative launch, 256 blocks x 512 thr, 1 block/CU (144KB dynamic LDS).
// Block bx owns hh pair (2bx, 2bx+1). Wave w = 64-k partition, both hh.
//
// Round-4 change: h is BULK-STAGED into LDS each step (16 independent
// float4 loads/thread, all in flight -> ~1 MALL latency instead of the
// k-loop's ~16 serialized load batches), FMA reads h from LDS
// (conflict-free b32: lane-consecutive). Weights stay on the wave-uniform
// s_load path (sL1-hot across steps).
//
// Barrier (proven in round 3): Hbuf[t+1] stored write-through via relaxed
// agent-scope atomics (no dirty L2 line, no wbl2); __syncthreads drains
// vmcnt; relaxed agent flag store + relaxed agent poll; no acquire fence
// needed because each step's h lines are fresh addresses (never cached
// by any L1/L2 this launch) -> plain loads fetch the MALL copy.
__global__ __launch_bounds__(512) void lstm_rec(
    const float* __restrict__ G_T, const float* __restrict__ WhhG,
    float* __restrict__ Hbuf, float* __restrict__ cT,
    float* __restrict__ Fbuf, float* __restrict__ Dbuf,
    int* __restrict__ bar) {
  extern __shared__ float lds[];
  float* hlds = lds;           // [512][64] h tile = 32768 floats (128KB)
  float* red = lds + 32768;    // [8 kp][8 j][64 b] = 4096 floats (16KB)
  int tid = threadIdx.x;
  int lane = tid & 63;
  int wave = __builtin_amdgcn_readfirstlane(tid >> 6);  // 0..7 = k-partition
  int bx = blockIdx.x;
  const float* wp = WhhG + (long)(wave * 64) * G4H + bx * 8;
  int h2 = tid >> 6;  // 0/1 for tid<128
  int b = tid & 63;
  float creg = 0.f;
  if (tid < 128) creg = cT[(bx * 2 + h2) * BB + b];

  // Prefetch step-0 x-gate precomputes (G_T is static during this kernel).
  float gpre0 = 0.f, gpre1 = 0.f, gpre2 = 0.f, gpre3 = 0.f;
  if (tid < 128) {
    const float* gp = G_T + (bx * 2 + h2) * BB + b;
    gpre0 = gp[0l * HH * BB];
    gpre1 = gp[1l * HH * BB];
    gpre2 = gp[2l * HH * BB];
    gpre3 = gp[3l * HH * BB];
  }

  // Prologue: stage h(0) into LDS (written by tp64, normal cached lines).
  {
    const float4* hsrc = (const float4*)Hbuf;
    float4* hdst = (float4*)hlds;
#pragma unroll
    for (int i = 0; i < 16; ++i) {
      int gi = i * 512 + tid;
      hdst[gi] = hsrc[gi];
    }
  }
  __syncthreads();

  for (int t = 0; t < TT; ++t) {
    // Partial dot products over this wave's 64 k (h from LDS), both hh.
    float a0 = 0.f, a1 = 0.f, a2 = 0.f, a3 = 0.f;
    float a4 = 0.f, a5 = 0.f, a6 = 0.f, a7 = 0.f;
    const float* hl = hlds + (wave * 64) * BB + lane;
#pragma unroll 8
    for (int k = 0; k < 64; ++k) {
      float h = hl[k * BB];
      float4 w0 = *(const float4*)(wp + (long)k * G4H);
      float4 w1 = *(const float4*)(wp + (long)k * G4H + 4);
      a0 = fmaf(w0.x, h, a0); a1 = fmaf(w0.y, h, a1);
      a2 = fmaf(w0.z, h, a2); a3 = fmaf(w0.w, h, a3);
      a4 = fmaf(w1.x, h, a4); a5 = fmaf(w1.y, h, a5);
      a6 = fmaf(w1.z, h, a6); a7 = fmaf(w1.w, h, a7);
    }
    float* rw = red + (wave * 8) * 64 + lane;
    rw[0 * 64] = a0; rw[1 * 64] = a1; rw[2 * 64] = a2; rw[3 * 64] = a3;
    rw[4 * 64] = a4; rw[5 * 64] = a5; rw[6 * 64] = a6; rw[7 * 64] = a7;
    __syncthreads();
    if (tid < 128) {
      float g0 = gpre0, g1 = gpre1, g2 = gpre2, g3 = gpre3;
#pragma unroll
      for (int kp = 0; kp < 8; ++kp) {
        const float* rr = red + (kp * 8 + h2 * 4) * 64 + b;
        g0 += rr[0 * 64];
        g1 += rr[1 * 64];
        g2 += rr[2 * 64];
        g3 += rr[3 * 64];
      }
      float ig = 1.f / (1.f + expf(-g0));
      float fg = 1.f / (1.f + expf(-g1));
      float gg = tanhf(g2);
      float og = 1.f / (1.f + expf(-g3));
      int idx = (bx * 2 + h2) * BB + b;
      float co = creg;
      float cy = fg * co + ig * gg;
      creg = cy;
      // Write-through (agent-relaxed): h at MALL once vmcnt drains.
      __hip_atomic_store(&Hbuf[(long)(t + 1) * (HH * BB) + idx],
                         og * tanhf(cy), __ATOMIC_RELAXED,
                         __HIP_MEMORY_SCOPE_AGENT);
      Fbuf[(long)t * (HH * BB) + idx] = fg;
      float* dp = Dbuf + (long)t * (G3H * BB) + idx;
      dp[0] = gg * ig * (1.f - ig);
      dp[HH * BB] = co * fg * (1.f - fg);
      dp[2 * HH * BB] = ig * (1.f - gg * gg);
    }
    // Drain all waves' stores, then signal + prefetch + wait + stage.
    __syncthreads();
    if (t < TT - 1) {
      if (tid == 0)
        __hip_atomic_store(&bar[bx], t + 1, __ATOMIC_RELAXED,
                           __HIP_MEMORY_SCOPE_AGENT);
      // Prefetch next step's x-gate precomputes under the barrier wait.
      if (tid < 128) {
        const float* gp =
            G_T + (long)(t + 1) * (G4H * BB) + (bx * 2 + h2) * BB + b;
        gpre0 = gp[0l * HH * BB];
        gpre1 = gp[1l * HH * BB];
        gpre2 = gp[2l * HH * BB];
        gpre3 = gp[3l * HH * BB];
      }
      if (tid < 64) {
        int tgt = t + 1;
        while (true) {
          int v0 = __hip_atomic_load(&bar[lane], __ATOMIC_RELAXED,
                                     __HIP_MEMORY_SCOPE_AGENT);
          int v1 = __hip_atomic_load(&bar[lane + 64], __ATOMIC_RELAXED,
                                     __HIP_MEMORY_SCOPE_AGENT);
          int v2 = __hip_atomic_load(&bar[lane + 128], __ATOMIC_RELAXED,
                                     __HIP_MEMORY_SCOPE_AGENT);
          int v3 = __hip_atomic_load(&bar[lane + 192], __ATOMIC_RELAXED,
                                     __HIP_MEMORY_SCOPE_AGENT);
          bool ok = (v0 >= tgt) && (v1 >= tgt) && (v2 >= tgt) && (v3 >= tgt);
          if (__all(ok)) break;
          __builtin_amdgcn_s_sleep(1);
        }
      }
      asm volatile("" ::: "memory");
      __syncthreads();
      // Bulk-stage h(t+1): 16 independent float4 loads/thread, all in
      // flight at once -> one MALL/L2 latency, not 16 serialized.
      {
        const float4* hsrc = (const float4*)(Hbuf + (long)(t + 1) * (HH * BB));
        float4* hdst = (float4*)hlds;
#pragma unroll
        for (int i = 0; i < 16; ++i) {
          int gi = i * 512 + tid;
          hdst[gi] = hsrc[gi];
        }
      }
      __syncthreads();
    }
  }
  if (tid < 128) cT[(bx * 2 + h2) * BB + b] = creg;
}

// Backward suffix scan: Dbuf[t] *= P_t; also emits ev_b.
__global__ __launch_bounds__(256) void suffix_scale(float* __restrict__ Dbuf,
                                                    const float* __restrict__ Fbuf,
                                                    float* __restrict__ evb) {
  int g = blockIdx.x * 256 + threadIdx.x;
  int b = g & 63, hh = g >> 6;
  float P = 1.f, e0 = 0.f, e1 = 0.f, e2 = 0.f;
#pragma unroll 2
  for (int t = TT - 1; t >= 0; --t) {
    float* dp = Dbuf + (long)t * (G3H * BB) + hh * BB + b;
    float v0 = dp[0] * P, v1 = dp[HH * BB] * P, v2 = dp[2 * HH * BB] * P;
    dp[0] = v0; dp[HH * BB] = v1; dp[2 * HH * BB] = v2;
    e0 += v0; e1 += v1; e2 += v2;
    P *= Fbuf[(long)t * (HH * BB) + hh * BB + b];
  }
  evb[b * G3H + hh] = e0;
  evb[b * G3H + HH + hh] = e1;
  evb[b * G3H + 2 * HH + hh] = e2;
}

extern "C" void kernel_launch(void* const* d_in, const int* in_sizes, int n_in,
                              void* d_out, int out_size, void* d_ws, size_t ws_size,
                              hipStream_t stream) {
  const float* x   = (const float*)d_in[0];  // [T][B][I]
  const float* h0  = (const float*)d_in[1];  // [B][H]
  const float* c0  = (const float*)d_in[2];  // [B][H]
  const float* Wih = (const float*)d_in[3];  // [4H][I]
  const float* Whh = (const float*)d_in[4];  // [4H][H]
  const float* bih = (const float*)d_in[5];
  const float* bhh = (const float*)d_in[6];
  float* out = (float*)d_out;
  float* ws = (float*)d_ws;

  float* G_T   = ws + OFF_GT;
  float* DbufT = ws + OFF_GT;    // aliases G_T (G_T dead after step loop)
  float* Hbuf  = ws + OFF_HBUF;
  float* Fbuf  = ws + OFF_FBUF;
  float* Dbuf  = ws + OFF_DBUF;
  float* cT    = ws + OFF_CT;
  float* xT    = ws + OFF_XT;
  float* WhhG  = ws + OFF_XT;    // aliases xT (xT dead after gx GEMM)
  float* WihT  = ws + OFF_WIHT;
  int*   bar   = (int*)(ws + OFF_WIHT);  // aliases WihT (dead after gx GEMM)
  float* WhhT  = ws + OFF_WHHT;

  // ---- prep transposes ----
  tp64<<<dim3(II / 64, G4H / 64, 1), 256, 0, stream>>>(Wih, WihT, G4H, II, 0, 0);
  tp64<<<dim3(HH / 64, G4H / 64, 1), 256, 0, stream>>>(Whh, WhhT, G4H, HH, 0, 0);
  tp64<<<dim3(II / 64, 1, TT), 256, 0, stream>>>(x, xT, BB, II, BB * II, BB * II);
  tp64<<<dim3(HH / 64, 1, 1), 256, 0, stream>>>(h0, Hbuf, BB, HH, 0, 0);
  tp64<<<dim3(HH / 64, 1, 1), 256, 0, stream>>>(c0, cT, BB, HH, 0, 0);

  // ---- G = x @ Wih^T + biases, layout [t][j][b] ----
  // C[m=j 2048][n=b 64] = sum_k WihT[k][j] * xT[t][k][b], K=256
  gemm_tn<64, 4, true, false><<<dim3(G4H / 64, 1, TT), 256, 0, stream>>>(
      WihT, 0, G4H, xT, (long)II * BB, BB, nullptr, 0,
      G_T, (long)G4H * BB, BB, bih, bhh);

  // ---- gate-interleave Whh + zero barrier slots (after gx: WihT/xT dead) ----
  make_whhg<<<dim3(HH * G4H / 256, 1, 1), 256, 0, stream>>>(WhhT, WhhG, bar);

  // ---- fused sequential recurrence: ONE cooperative kernel, 100 steps ----
  {
    const int shmem = (32768 + 4096) * 4;  // 144 KB dynamic LDS
    hipFuncSetAttribute((const void*)lstm_rec,
                        hipFuncAttributeMaxDynamicSharedMemorySize, shmem);
    const float* a_gt = G_T;
    const float* a_wg = WhhG;
    float* a_hb = Hbuf;
    float* a_ct = cT;
    float* a_fb = Fbuf;
    float* a_db = Dbuf;
    int* a_bar = bar;
    void* args[] = {(void*)&a_gt, (void*)&a_wg, (void*)&a_hb, (void*)&a_ct,
                    (void*)&a_fb, (void*)&a_db, (void*)&a_bar};
    hipLaunchCooperativeKernel((const void*)lstm_rec, dim3(NBLK), dim3(512),
                               args, shmem, stream);
  }

  // ---- backward suffix scaling (+ ev_b) ----
  suffix_scale<<<dim3(HH * BB / 256, 1, 1), 256, 0, stream>>>(Dbuf, Fbuf,
                                                              out + O_EVB);

  // ---- Dbuf [T*3H][B] -> DbufT [B][T*3H] (into dead G_T region) ----
  tp64<<<dim3(1, TT * G3H / 64, 1), 256, 0, stream>>>(Dbuf, DbufT, TT * G3H, BB,
                                                      0, 0);

  // ---- outputs + cx ----
  tp64<<<dim3(1, HH / 64, TT), 256, 0, stream>>>(Hbuf + HH * BB, out + O_OUT,
                                                 HH, BB, HH * BB, HH * BB);
  tp64<<<dim3(1, HH / 64, 1), 256, 0, stream>>>(cT, out + O_CX, HH, BB, 0, 0);

  // ---- ev_ih[b][j][i] = sum_t DbufT[b][t][j] * x[t][b][i], K=100 ----
  gemm_tn<20, 5, false, false><<<dim3(G3H / 64, II / 64, BB), 256, 0, stream>>>(
      DbufT, (long)TT * G3H, G3H, x, (long)II, (long)BB * II, nullptr, 0,
      out + O_EVIH, (long)G3H * II, II, nullptr, nullptr);

  // ---- ev_hh[b][j][k] = sum_t DbufT[b][t][j] * h_{t-1}[b][k], K=100 ----
  gemm_tn<20, 5, false, true><<<dim3(G3H / 64, HH / 64, BB), 256, 0, stream>>>(
      DbufT, (long)TT * G3H, G3H, out + O_OUT, (long)HH, (long)BB * HH,
      h0, (long)HH,
      out + O_EVHH, (long)G3H * HH, HH, nullptr, nullptr);
}

// Round 5
// 1568.055 us; speedup vs baseline: 1.0721x; 1.0721x over previous
//
#include <hip/hip_runtime.h>
#include <math.h>

// Problem dims
#define TT 100
#define BB 64
#define II 256
#define HH 512
#define G4H 2048   // 4H
#define G3H 1536   // 3H
#define NBLK 256   // persistent recurrence blocks (= HH/2)

// ---- workspace layout (float offsets) ----
// G_T   [T][4H][B]   gates from x@Wih^T + biases, layout [t][j][b]
// DbufT [B][T][3H]   (aliases G_T region after step loop — G_T dead by then)
// Hbuf  [T+1][H][B]  h history transposed; slot 0 = initial_h^T
// Fbuf  [T][H][B]    f gates
// Dbuf  [T][3H][B]   d values (scaled in-place to \tilde{d})
// cT    [H][B]
// xT    [T][I][B]    (WhhG aliases xT region after gx GEMM — xT dead by then)
// WihT  [I][4H]      (bar[] aliases WihT after gx GEMM — WihT dead by then)
// WhhT  [H][4H]
#define OFF_GT    0
#define OFF_HBUF  13107200
#define OFF_FBUF  16416768
#define OFF_DBUF  19693568
#define OFF_CT    29523968
#define OFF_XT    29556736
#define OFF_WIHT  31195136
#define OFF_WHHT  31719424

// ---- output layout (float offsets in d_out) ----
#define O_OUT   0          // outputs [T][B][H]
#define O_CX    3276800    // cx [B][H]
#define O_EVIH  3309568    // ev_ih [B][3H][I]
#define O_EVHH  28475392   // ev_hh [B][3H][H]
#define O_EVB   78807040   // ev_b  [B][3H]

// Generic 64x64 tiled transpose: dst[c][r] = src[r][c]. R,C multiples of 64.
__global__ __launch_bounds__(256) void tp64(const float* __restrict__ src,
                                            float* __restrict__ dst,
                                            int R, int C,
                                            long sstride, long dstride) {
  __shared__ float tile[64][65];
  src += (long)blockIdx.z * sstride;
  dst += (long)blockIdx.z * dstride;
  int r0 = blockIdx.y * 64, c0 = blockIdx.x * 64;
  int tx = threadIdx.x & 15, tq = threadIdx.x >> 4;
#pragma unroll
  for (int p = 0; p < 4; ++p) {
    int rl = p * 16 + tq;
    float4 v = *(const float4*)(src + (long)(r0 + rl) * C + c0 + tx * 4);
    tile[rl][tx * 4 + 0] = v.x; tile[rl][tx * 4 + 1] = v.y;
    tile[rl][tx * 4 + 2] = v.z; tile[rl][tx * 4 + 3] = v.w;
  }
  __syncthreads();
#pragma unroll
  for (int p = 0; p < 4; ++p) {
    int cl = p * 16 + tq;
    float4 v;
    v.x = tile[tx * 4 + 0][cl]; v.y = tile[tx * 4 + 1][cl];
    v.z = tile[tx * 4 + 2][cl]; v.w = tile[tx * 4 + 3][cl];
    *(float4*)(dst + (long)(c0 + cl) * R + r0 + tx * 4) = v;
  }
}

// WhhG[k][hh*4+g] = WhhT[k][g*512+hh]  (gate-interleaved for uniform dwordx4)
// Also zeroes the barrier slots (bar aliases dead WihT) for this replay.
__global__ __launch_bounds__(256) void make_whhg(const float* __restrict__ WhhT,
                                                 float* __restrict__ WhhG,
                                                 int* __restrict__ bar) {
  int gid = blockIdx.x * 256 + threadIdx.x;  // 512*2048 total
  if (gid < NBLK) bar[gid] = 0;
  int k = gid >> 11, j = gid & 2047;
  float v = WhhT[gid];
  WhhG[(long)k * G4H + ((j & 511) << 2) + (j >> 9)] = v;
}

// Tiled TN GEMM: C[m][n] = sum_k A[k][m] * Z[k][n]  (+ bias[m] if BIAS).
// Both operands stored K-major. 64x64 C-tile, 256 thr, 4x4 outputs/thread.
// ZSHIFT: Z row k maps to (k==0 ? Z0 : Z + (k-1)*ldz)  [for h_{t-1} history].
template <int BK, int KTILES, bool BIAS, bool ZSHIFT>
__global__ __launch_bounds__(256) void gemm_tn(
    const float* __restrict__ A, long batchA, int lda,
    const float* __restrict__ Z, long batchZ, int ldz,
    const float* __restrict__ Z0, long batchZ0,
    float* __restrict__ C, long batchC, int ldc,
    const float* __restrict__ bia, const float* __restrict__ bib) {
  __shared__ float As[BK][64];
  __shared__ float Zs[BK][64];
  int tid = threadIdx.x;
  int tn = tid & 15, tm = tid >> 4;
  int m0 = blockIdx.x * 64, n0 = blockIdx.y * 64;
  long bz = blockIdx.z;
  const float* Ab = A + bz * batchA + m0;
  const float* Zb = Z + bz * batchZ + n0;
  const float* Z0b = ZSHIFT ? (Z0 + bz * batchZ0 + n0) : nullptr;
  float acc[4][4] = {};
  for (int kt = 0; kt < KTILES; ++kt) {
    int k0 = kt * BK;
#pragma unroll
    for (int p = tid; p < BK * 64; p += 256) {
      int r = p >> 6, c = p & 63;
      int k = k0 + r;
      As[r][c] = Ab[(long)k * lda + c];
      const float* zr;
      if (ZSHIFT)
        zr = (k == 0) ? Z0b : (Zb + (long)(k - 1) * ldz);
      else
        zr = Zb + (long)k * ldz;
      Zs[r][c] = zr[c];
    }
    __syncthreads();
#pragma unroll 4
    for (int kk = 0; kk < BK; ++kk) {
      float4 a = *(const float4*)&As[kk][tm * 4];
      float4 z = *(const float4*)&Zs[kk][tn * 4];
      float av[4] = {a.x, a.y, a.z, a.w};
      float zv[4] = {z.x, z.y, z.z, z.w};
#pragma unroll
      for (int q = 0; q < 4; ++q)
#pragma unroll
        for (int r = 0; r < 4; ++r)
          acc[q][r] = fmaf(av[q], zv[r], acc[q][r]);
    }
    __syncthreads();
  }
  float* Cb = C + bz * batchC + n0 + tn * 4;
#pragma unroll
  for (int q = 0; q < 4; ++q) {
    int m = m0 + tm * 4 + q;
    float bv = BIAS ? (bia[m] + bib[m]) : 0.f;
    float4 v;
    v.x = acc[q][0] + bv; v.y = acc[q][1] + bv;
    v.z = acc[q][2] + bv; v.w = acc[q][3] + bv;
    *(float4*)(Cb + (long)m * ldc) = v;
  }
}

// ---- Persistent fused recurrence: all 100 steps in ONE kernel. ----
// Cooperative launch, 256 blocks x 512 thr (8 waves), 1 block/CU.
// Block bx owns hh pair (2bx, 2bx+1). Wave w = 64-k partition, both hh.
//
// Round-5 structure (round-3 base + latency fixes):
//  - Register-stage h: hv[64] fully-unrolled loads => all 64 loads in
//    flight (one exposed L2/MALL latency, not ~16 serialized batches).
//  - Per-wave producer-set polling: wave w consumes h rows
//    [w*64, w*64+64) produced only by blocks [32w, 32w+32) => poll just
//    those 32 flags (1 load/lane) and start FMA as soon as THEY are done.
//    Cross-block skew becomes pipelining instead of a global max.
//  - No post-poll __syncthreads: red[] writes for step t+1 occur long
//    after step-t readers finished (they read before the drain barrier).
//
// Barrier memory scheme (proven round 3): Hbuf[t+1] stored write-through
// via relaxed agent-scope atomics (no dirty L2 line, no wbl2);
// __syncthreads drains vmcnt => h at MALL before the relaxed flag store;
// relaxed agent poll; no acquire fence needed because each step's h lines
// are fresh addresses (never cached by any L1/L2 this launch).
__global__ __launch_bounds__(512) void lstm_rec(
    const float* __restrict__ G_T, const float* __restrict__ WhhG,
    float* __restrict__ Hbuf, float* __restrict__ cT,
    float* __restrict__ Fbuf, float* __restrict__ Dbuf,
    int* __restrict__ bar) {
  __shared__ float red[8][8][64];  // [kp][gate-row j][b]
  int tid = threadIdx.x;
  int lane = tid & 63;
  int wave = __builtin_amdgcn_readfirstlane(tid >> 6);  // 0..7 = k-partition
  int bx = blockIdx.x;
  const float* wp = WhhG + (long)(wave * 64) * G4H + bx * 8;
  int h2 = tid >> 6;  // 0/1 for tid<128
  int b = tid & 63;
  float creg = 0.f;
  if (tid < 128) creg = cT[(bx * 2 + h2) * BB + b];

  // Prefetch step-0 x-gate precomputes (G_T is static during this kernel).
  float gpre0 = 0.f, gpre1 = 0.f, gpre2 = 0.f, gpre3 = 0.f;
  if (tid < 128) {
    const float* gp = G_T + (bx * 2 + h2) * BB + b;
    gpre0 = gp[0l * HH * BB];
    gpre1 = gp[1l * HH * BB];
    gpre2 = gp[2l * HH * BB];
    gpre3 = gp[3l * HH * BB];
  }

  // This wave's producer-flag slot: blocks [32*wave, 32*wave+32).
  int myflag = wave * 32 + (lane & 31);

  for (int t = 0; t < TT; ++t) {
    // Register-stage this wave's 64-row h slice: all loads in flight.
    const float* hp = Hbuf + (long)t * (HH * BB) + (wave * 64) * BB + lane;
    float hv[64];
#pragma unroll
    for (int k = 0; k < 64; ++k) hv[k] = hp[(long)k * BB];
    // Partial dot products, both hh, 4 gates each (weights via s_load).
    float a0 = 0.f, a1 = 0.f, a2 = 0.f, a3 = 0.f;
    float a4 = 0.f, a5 = 0.f, a6 = 0.f, a7 = 0.f;
#pragma unroll
    for (int k = 0; k < 64; ++k) {
      float h = hv[k];
      float4 w0 = *(const float4*)(wp + (long)k * G4H);
      float4 w1 = *(const float4*)(wp + (long)k * G4H + 4);
      a0 = fmaf(w0.x, h, a0); a1 = fmaf(w0.y, h, a1);
      a2 = fmaf(w0.z, h, a2); a3 = fmaf(w0.w, h, a3);
      a4 = fmaf(w1.x, h, a4); a5 = fmaf(w1.y, h, a5);
      a6 = fmaf(w1.z, h, a6); a7 = fmaf(w1.w, h, a7);
    }
    red[wave][0][lane] = a0; red[wave][1][lane] = a1;
    red[wave][2][lane] = a2; red[wave][3][lane] = a3;
    red[wave][4][lane] = a4; red[wave][5][lane] = a5;
    red[wave][6][lane] = a6; red[wave][7][lane] = a7;
    __syncthreads();
    if (tid < 128) {
      float g0 = gpre0, g1 = gpre1, g2 = gpre2, g3 = gpre3;
#pragma unroll
      for (int kp = 0; kp < 8; ++kp) {
        g0 += red[kp][h2 * 4 + 0][b];
        g1 += red[kp][h2 * 4 + 1][b];
        g2 += red[kp][h2 * 4 + 2][b];
        g3 += red[kp][h2 * 4 + 3][b];
      }
      float ig = 1.f / (1.f + expf(-g0));
      float fg = 1.f / (1.f + expf(-g1));
      float gg = tanhf(g2);
      float og = 1.f / (1.f + expf(-g3));
      int idx = (bx * 2 + h2) * BB + b;
      float co = creg;
      float cy = fg * co + ig * gg;
      creg = cy;
      // Write-through (agent-relaxed): h at MALL once vmcnt drains.
      __hip_atomic_store(&Hbuf[(long)(t + 1) * (HH * BB) + idx],
                         og * tanhf(cy), __ATOMIC_RELAXED,
                         __HIP_MEMORY_SCOPE_AGENT);
      Fbuf[(long)t * (HH * BB) + idx] = fg;
      float* dp = Dbuf + (long)t * (G3H * BB) + idx;
      dp[0] = gg * ig * (1.f - ig);
      dp[HH * BB] = co * fg * (1.f - fg);
      dp[2 * HH * BB] = ig * (1.f - gg * gg);
    }
    // Drain all waves' stores (vmcnt(0) before s_barrier) => h at MALL.
    __syncthreads();
    if (t < TT - 1) {
      if (tid == 0)
        __hip_atomic_store(&bar[bx], t + 1, __ATOMIC_RELAXED,
                           __HIP_MEMORY_SCOPE_AGENT);
      // Prefetch next step's x-gate precomputes under the poll wait.
      if (tid < 128) {
        const float* gp =
            G_T + (long)(t + 1) * (G4H * BB) + (bx * 2 + h2) * BB + b;
        gpre0 = gp[0l * HH * BB];
        gpre1 = gp[1l * HH * BB];
        gpre2 = gp[2l * HH * BB];
        gpre3 = gp[3l * HH * BB];
      }
      // Per-wave poll: only this wave's 32 producer blocks.
      {
        int tgt = t + 1;
        while (true) {
          int v = __hip_atomic_load(&bar[myflag], __ATOMIC_RELAXED,
                                    __HIP_MEMORY_SCOPE_AGENT);
          if (__all(v >= tgt)) break;
          __builtin_amdgcn_s_sleep(1);
        }
      }
      asm volatile("" ::: "memory");  // keep h loads after the poll
    }
  }
  if (tid < 128) cT[(bx * 2 + h2) * BB + b] = creg;
}

// Backward suffix scan: Dbuf[t] *= P_t; also emits ev_b.
__global__ __launch_bounds__(256) void suffix_scale(float* __restrict__ Dbuf,
                                                    const float* __restrict__ Fbuf,
                                                    float* __restrict__ evb) {
  int g = blockIdx.x * 256 + threadIdx.x;
  int b = g & 63, hh = g >> 6;
  float P = 1.f, e0 = 0.f, e1 = 0.f, e2 = 0.f;
#pragma unroll 2
  for (int t = TT - 1; t >= 0; --t) {
    float* dp = Dbuf + (long)t * (G3H * BB) + hh * BB + b;
    float v0 = dp[0] * P, v1 = dp[HH * BB] * P, v2 = dp[2 * HH * BB] * P;
    dp[0] = v0; dp[HH * BB] = v1; dp[2 * HH * BB] = v2;
    e0 += v0; e1 += v1; e2 += v2;
    P *= Fbuf[(long)t * (HH * BB) + hh * BB + b];
  }
  evb[b * G3H + hh] = e0;
  evb[b * G3H + HH + hh] = e1;
  evb[b * G3H + 2 * HH + hh] = e2;
}

extern "C" void kernel_launch(void* const* d_in, const int* in_sizes, int n_in,
                              void* d_out, int out_size, void* d_ws, size_t ws_size,
                              hipStream_t stream) {
  const float* x   = (const float*)d_in[0];  // [T][B][I]
  const float* h0  = (const float*)d_in[1];  // [B][H]
  const float* c0  = (const float*)d_in[2];  // [B][H]
  const float* Wih = (const float*)d_in[3];  // [4H][I]
  const float* Whh = (const float*)d_in[4];  // [4H][H]
  const float* bih = (const float*)d_in[5];
  const float* bhh = (const float*)d_in[6];
  float* out = (float*)d_out;
  float* ws = (float*)d_ws;

  float* G_T   = ws + OFF_GT;
  float* DbufT = ws + OFF_GT;    // aliases G_T (G_T dead after step loop)
  float* Hbuf  = ws + OFF_HBUF;
  float* Fbuf  = ws + OFF_FBUF;
  float* Dbuf  = ws + OFF_DBUF;
  float* cT    = ws + OFF_CT;
  float* xT    = ws + OFF_XT;
  float* WhhG  = ws + OFF_XT;    // aliases xT (xT dead after gx GEMM)
  float* WihT  = ws + OFF_WIHT;
  int*   bar   = (int*)(ws + OFF_WIHT);  // aliases WihT (dead after gx GEMM)
  float* WhhT  = ws + OFF_WHHT;

  // ---- prep transposes ----
  tp64<<<dim3(II / 64, G4H / 64, 1), 256, 0, stream>>>(Wih, WihT, G4H, II, 0, 0);
  tp64<<<dim3(HH / 64, G4H / 64, 1), 256, 0, stream>>>(Whh, WhhT, G4H, HH, 0, 0);
  tp64<<<dim3(II / 64, 1, TT), 256, 0, stream>>>(x, xT, BB, II, BB * II, BB * II);
  tp64<<<dim3(HH / 64, 1, 1), 256, 0, stream>>>(h0, Hbuf, BB, HH, 0, 0);
  tp64<<<dim3(HH / 64, 1, 1), 256, 0, stream>>>(c0, cT, BB, HH, 0, 0);

  // ---- G = x @ Wih^T + biases, layout [t][j][b] ----
  // C[m=j 2048][n=b 64] = sum_k WihT[k][j] * xT[t][k][b], K=256
  gemm_tn<64, 4, true, false><<<dim3(G4H / 64, 1, TT), 256, 0, stream>>>(
      WihT, 0, G4H, xT, (long)II * BB, BB, nullptr, 0,
      G_T, (long)G4H * BB, BB, bih, bhh);

  // ---- gate-interleave Whh + zero barrier slots (after gx: WihT/xT dead) ----
  make_whhg<<<dim3(HH * G4H / 256, 1, 1), 256, 0, stream>>>(WhhT, WhhG, bar);

  // ---- fused sequential recurrence: ONE cooperative kernel, 100 steps ----
  {
    const float* a_gt = G_T;
    const float* a_wg = WhhG;
    float* a_hb = Hbuf;
    float* a_ct = cT;
    float* a_fb = Fbuf;
    float* a_db = Dbuf;
    int* a_bar = bar;
    void* args[] = {(void*)&a_gt, (void*)&a_wg, (void*)&a_hb, (void*)&a_ct,
                    (void*)&a_fb, (void*)&a_db, (void*)&a_bar};
    hipLaunchCooperativeKernel((const void*)lstm_rec, dim3(NBLK), dim3(512),
                               args, 0, stream);
  }

  // ---- backward suffix scaling (+ ev_b) ----
  suffix_scale<<<dim3(HH * BB / 256, 1, 1), 256, 0, stream>>>(Dbuf, Fbuf,
                                                              out + O_EVB);

  // ---- Dbuf [T*3H][B] -> DbufT [B][T*3H] (into dead G_T region) ----
  tp64<<<dim3(1, TT * G3H / 64, 1), 256, 0, stream>>>(Dbuf, DbufT, TT * G3H, BB,
                                                      0, 0);

  // ---- outputs + cx ----
  tp64<<<dim3(1, HH / 64, TT), 256, 0, stream>>>(Hbuf + HH * BB, out + O_OUT,
                                                 HH, BB, HH * BB, HH * BB);
  tp64<<<dim3(1, HH / 64, 1), 256, 0, stream>>>(cT, out + O_CX, HH, BB, 0, 0);

  // ---- ev_ih[b][j][i] = sum_t DbufT[b][t][j] * x[t][b][i], K=100 ----
  gemm_tn<20, 5, false, false><<<dim3(G3H / 64, II / 64, BB), 256, 0, stream>>>(
      DbufT, (long)TT * G3H, G3H, x, (long)II, (long)BB * II, nullptr, 0,
      out + O_EVIH, (long)G3H * II, II, nullptr, nullptr);

  // ---- ev_hh[b][j][k] = sum_t DbufT[b][t][j] * h_{t-1}[b][k], K=100 ----
  gemm_tn<20, 5, false, true><<<dim3(G3H / 64, HH / 64, BB), 256, 0, stream>>>(
      DbufT, (long)TT * G3H, G3H, out + O_OUT, (long)HH, (long)BB * HH,
      h0, (long)HH,
      out + O_EVHH, (long)G3H * HH, HH, nullptr, nullptr);
}

// Round 6
// 1496.430 us; speedup vs baseline: 1.1234x; 1.0479x over previous
//
#include <hip/hip_runtime.h>
#include <math.h>

// Problem dims
#define TT 100
#define BB 64
#define II 256
#define HH 512
#define G4H 2048   // 4H
#define G3H 1536   // 3H
#define NBLK 256   // persistent recurrence blocks (= HH/2)

// ---- workspace layout (float offsets) ----
// G_T   [T][4H][B]   gates from x@Wih^T + biases, layout [t][j][b]
// DbufT [B][T][3H]   (aliases G_T region after step loop — G_T dead by then)
// Hbuf  [T+1][H][B]  h history transposed; slot 0 = initial_h^T
// Fbuf  [T][H][B]    f gates
// Dbuf  [T][3H][B]   d values (scaled in-place to \tilde{d})
// cT    [H][B]
// xT    [T][I][B]    (WhhG aliases xT region after gx GEMM — xT dead by then)
// WihT  [I][4H]      (bar[] aliases WihT after gx GEMM — WihT dead by then)
// WhhT  [H][4H]
#define OFF_GT    0
#define OFF_HBUF  13107200
#define OFF_FBUF  16416768
#define OFF_DBUF  19693568
#define OFF_CT    29523968
#define OFF_XT    29556736
#define OFF_WIHT  31195136
#define OFF_WHHT  31719424

// ---- output layout (float offsets in d_out) ----
#define O_OUT   0          // outputs [T][B][H]
#define O_CX    3276800    // cx [B][H]
#define O_EVIH  3309568    // ev_ih [B][3H][I]
#define O_EVHH  28475392   // ev_hh [B][3H][H]
#define O_EVB   78807040   // ev_b  [B][3H]

// Generic 64x64 tiled transpose: dst[c][r] = src[r][c]. R,C multiples of 64.
__global__ __launch_bounds__(256) void tp64(const float* __restrict__ src,
                                            float* __restrict__ dst,
                                            int R, int C,
                                            long sstride, long dstride) {
  __shared__ float tile[64][65];
  src += (long)blockIdx.z * sstride;
  dst += (long)blockIdx.z * dstride;
  int r0 = blockIdx.y * 64, c0 = blockIdx.x * 64;
  int tx = threadIdx.x & 15, tq = threadIdx.x >> 4;
#pragma unroll
  for (int p = 0; p < 4; ++p) {
    int rl = p * 16 + tq;
    float4 v = *(const float4*)(src + (long)(r0 + rl) * C + c0 + tx * 4);
    tile[rl][tx * 4 + 0] = v.x; tile[rl][tx * 4 + 1] = v.y;
    tile[rl][tx * 4 + 2] = v.z; tile[rl][tx * 4 + 3] = v.w;
  }
  __syncthreads();
#pragma unroll
  for (int p = 0; p < 4; ++p) {
    int cl = p * 16 + tq;
    float4 v;
    v.x = tile[tx * 4 + 0][cl]; v.y = tile[tx * 4 + 1][cl];
    v.z = tile[tx * 4 + 2][cl]; v.w = tile[tx * 4 + 3][cl];
    *(float4*)(dst + (long)(c0 + cl) * R + r0 + tx * 4) = v;
  }
}

// WhhG[k][hh*4+g] = WhhT[k][g*512+hh]  (gate-interleaved for uniform dwordx4)
// Also zeroes the 512 per-hh flag slots (bar aliases dead WihT).
__global__ __launch_bounds__(256) void make_whhg(const float* __restrict__ WhhT,
                                                 float* __restrict__ WhhG,
                                                 int* __restrict__ bar) {
  int gid = blockIdx.x * 256 + threadIdx.x;  // 512*2048 total
  if (gid < 2 * NBLK) bar[gid] = 0;
  int k = gid >> 11, j = gid & 2047;
  float v = WhhT[gid];
  WhhG[(long)k * G4H + ((j & 511) << 2) + (j >> 9)] = v;
}

// Tiled TN GEMM: C[m][n] = sum_k A[k][m] * Z[k][n]  (+ bias[m] if BIAS).
// Both operands stored K-major. 64x64 C-tile, 256 thr, 4x4 outputs/thread.
// ZSHIFT: Z row k maps to (k==0 ? Z0 : Z + (k-1)*ldz)  [for h_{t-1} history].
template <int BK, int KTILES, bool BIAS, bool ZSHIFT>
__global__ __launch_bounds__(256) void gemm_tn(
    const float* __restrict__ A, long batchA, int lda,
    const float* __restrict__ Z, long batchZ, int ldz,
    const float* __restrict__ Z0, long batchZ0,
    float* __restrict__ C, long batchC, int ldc,
    const float* __restrict__ bia, const float* __restrict__ bib) {
  __shared__ float As[BK][64];
  __shared__ float Zs[BK][64];
  int tid = threadIdx.x;
  int tn = tid & 15, tm = tid >> 4;
  int m0 = blockIdx.x * 64, n0 = blockIdx.y * 64;
  long bz = blockIdx.z;
  const float* Ab = A + bz * batchA + m0;
  const float* Zb = Z + bz * batchZ + n0;
  const float* Z0b = ZSHIFT ? (Z0 + bz * batchZ0 + n0) : nullptr;
  float acc[4][4] = {};
  for (int kt = 0; kt < KTILES; ++kt) {
    int k0 = kt * BK;
#pragma unroll
    for (int p = tid; p < BK * 64; p += 256) {
      int r = p >> 6, c = p & 63;
      int k = k0 + r;
      As[r][c] = Ab[(long)k * lda + c];
      const float* zr;
      if (ZSHIFT)
        zr = (k == 0) ? Z0b : (Zb + (long)(k - 1) * ldz);
      else
        zr = Zb + (long)k * ldz;
      Zs[r][c] = zr[c];
    }
    __syncthreads();
#pragma unroll 4
    for (int kk = 0; kk < BK; ++kk) {
      float4 a = *(const float4*)&As[kk][tm * 4];
      float4 z = *(const float4*)&Zs[kk][tn * 4];
      float av[4] = {a.x, a.y, a.z, a.w};
      float zv[4] = {z.x, z.y, z.z, z.w};
#pragma unroll
      for (int q = 0; q < 4; ++q)
#pragma unroll
        for (int r = 0; r < 4; ++r)
          acc[q][r] = fmaf(av[q], zv[r], acc[q][r]);
    }
    __syncthreads();
  }
  float* Cb = C + bz * batchC + n0 + tn * 4;
#pragma unroll
  for (int q = 0; q < 4; ++q) {
    int m = m0 + tm * 4 + q;
    float bv = BIAS ? (bia[m] + bib[m]) : 0.f;
    float4 v;
    v.x = acc[q][0] + bv; v.y = acc[q][1] + bv;
    v.z = acc[q][2] + bv; v.w = acc[q][3] + bv;
    *(float4*)(Cb + (long)m * ldc) = v;
  }
}

// ---- Persistent fused recurrence: all 100 steps in ONE kernel. ----
// Cooperative launch, 256 blocks x 640 thr (10 waves), 1 block/CU.
// Block bx owns hh pair (2bx, 2bx+1).
//
// Round-6 role split (the r4/r5 null results showed the serial per-step
// chain, not the h data path, is the bottleneck):
//   waves 0-7: FMA-only. At iteration t: poll own 64 per-hh flags (>= t),
//              load h(t) slice, FMA from LDS weights, write red[t&1].
//   waves 8-9: epilogue-only. At iteration t: reduce red[(t-1)&1] from
//              step t-1, activations, write-through h(t), in-wave vmcnt
//              drain (asm, no agent-release -> no wbl2), set flag[hh]=t,
//              prefetch G_T row t.
// ONE __syncthreads per iteration; epilogue(t-1) runs CONCURRENTLY with
// FMA(t) -> its ~2k-cycle tail comes off the critical path.
// red[] is double-buffered by t&1 (race-free across the single barrier).
// Weights live in LDS (16 KB, staged once): uniform-address ds_read_b128
// broadcast, off the (possibly CU-shared, thrashing) scalar-K$ path.
//
// Memory scheme (proven r3/r5): h write-through via relaxed agent atomics
// (no dirty L2 line); flags relaxed agent; poll loads bypass caches;
// h(t) lines are fresh addresses each step so plain cached loads fetch
// the MALL copy (and get L2-reused within an XCD).
__global__ __launch_bounds__(640) void lstm_rec(
    const float* __restrict__ G_T, const float* __restrict__ WhhG,
    float* __restrict__ Hbuf, float* __restrict__ cT,
    float* __restrict__ Fbuf, float* __restrict__ Dbuf,
    int* __restrict__ bar) {
  __shared__ float lds_w[4096];        // [k 512][8] this block's Whh slice
  __shared__ float red[2][8][8][64];   // [parity][kp][gate-row j][b]
  int tid = threadIdx.x;
  int lane = tid & 63;
  int wave = __builtin_amdgcn_readfirstlane(tid >> 6);  // 0..9
  int bx = blockIdx.x;

  // Stage this block's weight slice (16 KB) into LDS once.
  {
    float4* d4 = (float4*)lds_w;
    const float4* s4 = (const float4*)WhhG;  // [k][512 float4]
    for (int n = tid; n < 1024; n += 640) {
      int k = n >> 1, half = n & 1;
      d4[n] = s4[(long)k * 512 + bx * 2 + half];
    }
  }

  // Epilogue-wave state (waves 8,9): h2 = wave-8, lane = b.
  int h2 = wave - 8;
  int b = lane;
  float creg = 0.f;
  float gpre0 = 0.f, gpre1 = 0.f, gpre2 = 0.f, gpre3 = 0.f;
  if (wave >= 8) {
    creg = cT[(bx * 2 + h2) * BB + b];
    const float* gp = G_T + (bx * 2 + h2) * BB + b;  // G_T row 0
    gpre0 = gp[0l * HH * BB];
    gpre1 = gp[1l * HH * BB];
    gpre2 = gp[2l * HH * BB];
    gpre3 = gp[3l * HH * BB];
  }
  __syncthreads();

  for (int t = 0; t < TT; ++t) {
    if (wave < 8) {
      // ---- FMA path: compute step t partial sums ----
      if (t > 0) {
        int myflag = wave * 64 + lane;  // flag per hh == h row index
        while (true) {
          int v = __hip_atomic_load(&bar[myflag], __ATOMIC_RELAXED,
                                    __HIP_MEMORY_SCOPE_AGENT);
          if (__all(v >= t)) break;
          __builtin_amdgcn_s_sleep(1);
        }
        asm volatile("" ::: "memory");  // keep h loads after the poll
      }
      const float* hp = Hbuf + (long)t * (HH * BB) + (wave * 64) * BB + lane;
      float hv[64];
#pragma unroll
      for (int k = 0; k < 64; ++k) hv[k] = hp[(long)k * BB];
      float a0 = 0.f, a1 = 0.f, a2 = 0.f, a3 = 0.f;
      float a4 = 0.f, a5 = 0.f, a6 = 0.f, a7 = 0.f;
      const float4* w4 = (const float4*)lds_w + wave * 128;  // 64 k x 2
#pragma unroll
      for (int k = 0; k < 64; ++k) {
        float4 w0 = w4[2 * k];
        float4 w1 = w4[2 * k + 1];
        float h = hv[k];
        a0 = fmaf(w0.x, h, a0); a1 = fmaf(w0.y, h, a1);
        a2 = fmaf(w0.z, h, a2); a3 = fmaf(w0.w, h, a3);
        a4 = fmaf(w1.x, h, a4); a5 = fmaf(w1.y, h, a5);
        a6 = fmaf(w1.z, h, a6); a7 = fmaf(w1.w, h, a7);
      }
      int p = t & 1;
      red[p][wave][0][lane] = a0; red[p][wave][1][lane] = a1;
      red[p][wave][2][lane] = a2; red[p][wave][3][lane] = a3;
      red[p][wave][4][lane] = a4; red[p][wave][5][lane] = a5;
      red[p][wave][6][lane] = a6; red[p][wave][7][lane] = a7;
    } else if (t > 0) {
      // ---- Epilogue path: finish step t-1 (concurrent with FMA(t)) ----
      int p = (t - 1) & 1;
      float g0 = gpre0, g1 = gpre1, g2 = gpre2, g3 = gpre3;
#pragma unroll
      for (int kp = 0; kp < 8; ++kp) {
        g0 += red[p][kp][h2 * 4 + 0][b];
        g1 += red[p][kp][h2 * 4 + 1][b];
        g2 += red[p][kp][h2 * 4 + 2][b];
        g3 += red[p][kp][h2 * 4 + 3][b];
      }
      float ig = 1.f / (1.f + expf(-g0));
      float fg = 1.f / (1.f + expf(-g1));
      float gg = tanhf(g2);
      float og = 1.f / (1.f + expf(-g3));
      int idx = (bx * 2 + h2) * BB + b;
      float co = creg;
      float cy = fg * co + ig * gg;
      creg = cy;
      __hip_atomic_store(&Hbuf[(long)t * (HH * BB) + idx], og * tanhf(cy),
                         __ATOMIC_RELAXED, __HIP_MEMORY_SCOPE_AGENT);
      Fbuf[(long)(t - 1) * (HH * BB) + idx] = fg;
      float* dp = Dbuf + (long)(t - 1) * (G3H * BB) + idx;
      dp[0] = gg * ig * (1.f - ig);
      dp[HH * BB] = co * fg * (1.f - fg);
      dp[2 * HH * BB] = ig * (1.f - gg * gg);
      // In-wave drain of the write-through h stores (no wbl2), then flag.
      asm volatile("s_waitcnt vmcnt(0)" ::: "memory");
      if (lane == 0)
        __hip_atomic_store(&bar[bx * 2 + h2], t, __ATOMIC_RELAXED,
                           __HIP_MEMORY_SCOPE_AGENT);
      // Prefetch G_T row t (consumed next iteration).
      const float* gp = G_T + (long)t * (G4H * BB) + (bx * 2 + h2) * BB + b;
      gpre0 = gp[0l * HH * BB];
      gpre1 = gp[1l * HH * BB];
      gpre2 = gp[2l * HH * BB];
      gpre3 = gp[3l * HH * BB];
    }
    __syncthreads();
  }

  // Final epilogue: step TT-1 (red[(TT-1)&1], gpre = G_T row TT-1).
  if (wave >= 8) {
    int p = (TT - 1) & 1;
    float g0 = gpre0, g1 = gpre1, g2 = gpre2, g3 = gpre3;
#pragma unroll
    for (int kp = 0; kp < 8; ++kp) {
      g0 += red[p][kp][h2 * 4 + 0][b];
      g1 += red[p][kp][h2 * 4 + 1][b];
      g2 += red[p][kp][h2 * 4 + 2][b];
      g3 += red[p][kp][h2 * 4 + 3][b];
    }
    float ig = 1.f / (1.f + expf(-g0));
    float fg = 1.f / (1.f + expf(-g1));
    float gg = tanhf(g2);
    float og = 1.f / (1.f + expf(-g3));
    int idx = (bx * 2 + h2) * BB + b;
    float co = creg;
    float cy = fg * co + ig * gg;
    Hbuf[(long)TT * (HH * BB) + idx] = og * tanhf(cy);
    Fbuf[(long)(TT - 1) * (HH * BB) + idx] = fg;
    float* dp = Dbuf + (long)(TT - 1) * (G3H * BB) + idx;
    dp[0] = gg * ig * (1.f - ig);
    dp[HH * BB] = co * fg * (1.f - fg);
    dp[2 * HH * BB] = ig * (1.f - gg * gg);
    cT[idx] = cy;
  }
}

// Backward suffix scan: Dbuf[t] *= P_t; also emits ev_b.
__global__ __launch_bounds__(256) void suffix_scale(float* __restrict__ Dbuf,
                                                    const float* __restrict__ Fbuf,
                                                    float* __restrict__ evb) {
  int g = blockIdx.x * 256 + threadIdx.x;
  int b = g & 63, hh = g >> 6;
  float P = 1.f, e0 = 0.f, e1 = 0.f, e2 = 0.f;
#pragma unroll 2
  for (int t = TT - 1; t >= 0; --t) {
    float* dp = Dbuf + (long)t * (G3H * BB) + hh * BB + b;
    float v0 = dp[0] * P, v1 = dp[HH * BB] * P, v2 = dp[2 * HH * BB] * P;
    dp[0] = v0; dp[HH * BB] = v1; dp[2 * HH * BB] = v2;
    e0 += v0; e1 += v1; e2 += v2;
    P *= Fbuf[(long)t * (HH * BB) + hh * BB + b];
  }
  evb[b * G3H + hh] = e0;
  evb[b * G3H + HH + hh] = e1;
  evb[b * G3H + 2 * HH + hh] = e2;
}

extern "C" void kernel_launch(void* const* d_in, const int* in_sizes, int n_in,
                              void* d_out, int out_size, void* d_ws, size_t ws_size,
                              hipStream_t stream) {
  const float* x   = (const float*)d_in[0];  // [T][B][I]
  const float* h0  = (const float*)d_in[1];  // [B][H]
  const float* c0  = (const float*)d_in[2];  // [B][H]
  const float* Wih = (const float*)d_in[3];  // [4H][I]
  const float* Whh = (const float*)d_in[4];  // [4H][H]
  const float* bih = (const float*)d_in[5];
  const float* bhh = (const float*)d_in[6];
  float* out = (float*)d_out;
  float* ws = (float*)d_ws;

  float* G_T   = ws + OFF_GT;
  float* DbufT = ws + OFF_GT;    // aliases G_T (G_T dead after step loop)
  float* Hbuf  = ws + OFF_HBUF;
  float* Fbuf  = ws + OFF_FBUF;
  float* Dbuf  = ws + OFF_DBUF;
  float* cT    = ws + OFF_CT;
  float* xT    = ws + OFF_XT;
  float* WhhG  = ws + OFF_XT;    // aliases xT (xT dead after gx GEMM)
  float* WihT  = ws + OFF_WIHT;
  int*   bar   = (int*)(ws + OFF_WIHT);  // aliases WihT (dead after gx GEMM)
  float* WhhT  = ws + OFF_WHHT;

  // ---- prep transposes ----
  tp64<<<dim3(II / 64, G4H / 64, 1), 256, 0, stream>>>(Wih, WihT, G4H, II, 0, 0);
  tp64<<<dim3(HH / 64, G4H / 64, 1), 256, 0, stream>>>(Whh, WhhT, G4H, HH, 0, 0);
  tp64<<<dim3(II / 64, 1, TT), 256, 0, stream>>>(x, xT, BB, II, BB * II, BB * II);
  tp64<<<dim3(HH / 64, 1, 1), 256, 0, stream>>>(h0, Hbuf, BB, HH, 0, 0);
  tp64<<<dim3(HH / 64, 1, 1), 256, 0, stream>>>(c0, cT, BB, HH, 0, 0);

  // ---- G = x @ Wih^T + biases, layout [t][j][b] ----
  // C[m=j 2048][n=b 64] = sum_k WihT[k][j] * xT[t][k][b], K=256
  gemm_tn<64, 4, true, false><<<dim3(G4H / 64, 1, TT), 256, 0, stream>>>(
      WihT, 0, G4H, xT, (long)II * BB, BB, nullptr, 0,
      G_T, (long)G4H * BB, BB, bih, bhh);

  // ---- gate-interleave Whh + zero flag slots (after gx: WihT/xT dead) ----
  make_whhg<<<dim3(HH * G4H / 256, 1, 1), 256, 0, stream>>>(WhhT, WhhG, bar);

  // ---- fused sequential recurrence: ONE cooperative kernel, 100 steps ----
  {
    const float* a_gt = G_T;
    const float* a_wg = WhhG;
    float* a_hb = Hbuf;
    float* a_ct = cT;
    float* a_fb = Fbuf;
    float* a_db = Dbuf;
    int* a_bar = bar;
    void* args[] = {(void*)&a_gt, (void*)&a_wg, (void*)&a_hb, (void*)&a_ct,
                    (void*)&a_fb, (void*)&a_db, (void*)&a_bar};
    hipLaunchCooperativeKernel((const void*)lstm_rec, dim3(NBLK), dim3(640),
                               args, 0, stream);
  }

  // ---- backward suffix scaling (+ ev_b) ----
  suffix_scale<<<dim3(HH * BB / 256, 1, 1), 256, 0, stream>>>(Dbuf, Fbuf,
                                                              out + O_EVB);

  // ---- Dbuf [T*3H][B] -> DbufT [B][T*3H] (into dead G_T region) ----
  tp64<<<dim3(1, TT * G3H / 64, 1), 256, 0, stream>>>(Dbuf, DbufT, TT * G3H, BB,
                                                      0, 0);

  // ---- outputs + cx ----
  tp64<<<dim3(1, HH / 64, TT), 256, 0, stream>>>(Hbuf + HH * BB, out + O_OUT,
                                                 HH, BB, HH * BB, HH * BB);
  tp64<<<dim3(1, HH / 64, 1), 256, 0, stream>>>(cT, out + O_CX, HH, BB, 0, 0);

  // ---- ev_ih[b][j][i] = sum_t DbufT[b][t][j] * x[t][b][i], K=100 ----
  gemm_tn<20, 5, false, false><<<dim3(G3H / 64, II / 64, BB), 256, 0, stream>>>(
      DbufT, (long)TT * G3H, G3H, x, (long)II, (long)BB * II, nullptr, 0,
      out + O_EVIH, (long)G3H * II, II, nullptr, nullptr);

  // ---- ev_hh[b][j][k] = sum_t DbufT[b][t][j] * h_{t-1}[b][k], K=100 ----
  gemm_tn<20, 5, false, true><<<dim3(G3H / 64, HH / 64, BB), 256, 0, stream>>>(
      DbufT, (long)TT * G3H, G3H, out + O_OUT, (long)HH, (long)BB * HH,
      h0, (long)HH,
      out + O_EVHH, (long)G3H * HH, HH, nullptr, nullptr);
}